// Round 1
// baseline (523.904 us; speedup 1.0000x reference)
//
#include <hip/hip_runtime.h>
#include <hip/hip_bf16.h>

#define D 128

// ---------------- preprocessing ----------------

__global__ void deg_kernel(const int* __restrict__ src, const int* __restrict__ dst,
                           const float* __restrict__ ew,
                           float* __restrict__ dsrc, float* __restrict__ ddst,
                           int* __restrict__ cnt, int E) {
    int e = blockIdx.x * 256 + threadIdx.x;
    if (e >= E) return;
    float w = ew[e];
    atomicAdd(&dsrc[src[e]], w);
    atomicAdd(&ddst[dst[e]], w);
    atomicAdd(&cnt[dst[e]], 1);
}

// inclusive block scan of cnt -> tmp, block totals -> bsum
__global__ void scanA(const int* __restrict__ cnt, int* __restrict__ tmp,
                      int* __restrict__ bsum, int N) {
    __shared__ int s[256];
    int tid = threadIdx.x;
    int i = blockIdx.x * 256 + tid;
    int v = (i < N) ? cnt[i] : 0;
    s[tid] = v;
    __syncthreads();
    #pragma unroll
    for (int off = 1; off < 256; off <<= 1) {
        int t = (tid >= off) ? s[tid - off] : 0;
        __syncthreads();
        s[tid] += t;
        __syncthreads();
    }
    if (i < N) tmp[i] = s[tid];
    if (tid == 255) bsum[blockIdx.x] = s[255];
}

// exclusive scan of block sums (nb <= 256)
__global__ void scanB(const int* __restrict__ bsum, int* __restrict__ boff, int nb) {
    __shared__ int s[256];
    int tid = threadIdx.x;
    int v = (tid < nb) ? bsum[tid] : 0;
    s[tid] = v;
    __syncthreads();
    #pragma unroll
    for (int off = 1; off < 256; off <<= 1) {
        int t = (tid >= off) ? s[tid - off] : 0;
        __syncthreads();
        s[tid] += t;
        __syncthreads();
    }
    if (tid < nb) boff[tid] = s[tid] - v;  // exclusive
}

__global__ void scanC(const int* __restrict__ tmp, const int* __restrict__ boff,
                      int* __restrict__ rowp, int N) {
    int i = blockIdx.x * 256 + threadIdx.x;
    if (i < N) rowp[i + 1] = tmp[i] + boff[blockIdx.x];
    if (i == 0) rowp[0] = 0;
}

// scatter edges into CSR-by-dst, folding both-norm + 1/in_deg into the weight
__global__ void fill_kernel(const int* __restrict__ src, const int* __restrict__ dst,
                            const float* __restrict__ ew,
                            const float* __restrict__ dsrc, const float* __restrict__ ddst,
                            const int* __restrict__ cnt, const int* __restrict__ rowp,
                            int* __restrict__ fill, int* __restrict__ csrc,
                            float* __restrict__ cwt, int E) {
    int e = blockIdx.x * 256 + threadIdx.x;
    if (e >= E) return;
    int s = src[e], d = dst[e];
    float denom = sqrtf(fmaxf(dsrc[s] * ddst[d], 1e-12f));
    float w2 = ew[e] / denom / fmaxf((float)cnt[d], 1.0f);
    int p = rowp[d] + atomicAdd(&fill[d], 1);
    csrc[p] = s;
    cwt[p] = w2;
}

// ---------------- per-layer: aggregate (one wave per node) ----------------

__global__ void aggregate(const float* __restrict__ h, const int* __restrict__ rowp,
                          const int* __restrict__ csrc, const float* __restrict__ cwt,
                          float* __restrict__ neigh, int N) {
    int wave = (blockIdx.x * blockDim.x + threadIdx.x) >> 6;
    int lane = threadIdx.x & 63;
    if (wave >= N) return;
    int beg = rowp[wave], end = rowp[wave + 1];
    const float2* h2 = (const float2*)h;
    float ax0 = 0.f, ay0 = 0.f, ax1 = 0.f, ay1 = 0.f;
    int i = beg;
    for (; i + 2 <= end; i += 2) {
        int s0 = csrc[i], s1 = csrc[i + 1];
        float w0 = cwt[i], w1 = cwt[i + 1];
        float2 x0 = h2[(size_t)s0 * 64 + lane];
        float2 x1 = h2[(size_t)s1 * 64 + lane];
        ax0 += w0 * x0.x; ay0 += w0 * x0.y;
        ax1 += w1 * x1.x; ay1 += w1 * x1.y;
    }
    if (i < end) {
        int s0 = csrc[i];
        float w0 = cwt[i];
        float2 x0 = h2[(size_t)s0 * 64 + lane];
        ax0 += w0 * x0.x; ay0 += w0 * x0.y;
    }
    float2 acc;
    acc.x = ax0 + ax1;
    acc.y = ay0 + ay1;
    ((float2*)neigh)[(size_t)wave * 64 + lane] = acc;
}

// ---------------- per-layer: fused dual GEMM + bias + relu ----------------
// out[v][d] = sum_k h[v][k]*W1[k][d] + sum_k neigh[v][k]*W2[k][d] + b[d]
// BM=64, BN=128, BK=32; 256 threads; per-thread 8 rows x 4 cols.

#define BM 64
#define BK 32
#define ASTRIDE 68  // 272B row stride: 16B-aligned for b128 reads, breaks pow2 bank stride

__global__ __launch_bounds__(256) void sage_gemm(
    const float* __restrict__ A1, const float* __restrict__ A2,
    const float* __restrict__ W1, const float* __restrict__ W2,
    const float* __restrict__ bias, float* __restrict__ out, int N, int relu) {
    __shared__ float As[BK][ASTRIDE];
    __shared__ float Ws[BK][D];

    int tid = threadIdx.x;
    int row0 = blockIdx.x * BM;
    int tcol = tid & 31;   // col group: cols tcol*4 .. +3
    int trow = tid >> 5;   // row group: rows trow*8 .. +7

    float acc[8][4] = {};

    for (int kc = 0; kc < 8; ++kc) {
        const float* A = (kc < 4) ? A1 : A2;
        const float* W = (kc < 4) ? W1 : W2;
        int kbase = (kc & 3) * BK;

        // stage A tile (64 rows x 32 k), transposed into As[k][m]
        {
            int r = tid >> 3;
            int c4 = (tid & 7) * 4;
            #pragma unroll
            for (int half = 0; half < 2; ++half) {
                int rr = r + half * 32;
                int gr = row0 + rr;
                float4 v = {0.f, 0.f, 0.f, 0.f};
                if (gr < N) v = *(const float4*)(A + (size_t)gr * D + kbase + c4);
                As[c4 + 0][rr] = v.x;
                As[c4 + 1][rr] = v.y;
                As[c4 + 2][rr] = v.z;
                As[c4 + 3][rr] = v.w;
            }
        }
        // stage W tile (32 k x 128 n)
        {
            int c4 = (tid & 31) * 4;
            int kk0 = tid >> 5;
            #pragma unroll
            for (int i = 0; i < 4; ++i) {
                int kk = kk0 + i * 8;
                float4 v = *(const float4*)(W + (size_t)(kbase + kk) * D + c4);
                *(float4*)&Ws[kk][c4] = v;
            }
        }
        __syncthreads();

        #pragma unroll
        for (int k = 0; k < BK; ++k) {
            float4 a0 = *(const float4*)&As[k][trow * 8];
            float4 a1 = *(const float4*)&As[k][trow * 8 + 4];
            float4 w = *(const float4*)&Ws[k][tcol * 4];
            float am[8] = {a0.x, a0.y, a0.z, a0.w, a1.x, a1.y, a1.z, a1.w};
            float wn[4] = {w.x, w.y, w.z, w.w};
            #pragma unroll
            for (int m = 0; m < 8; ++m)
                #pragma unroll
                for (int n = 0; n < 4; ++n)
                    acc[m][n] += am[m] * wn[n];
        }
        __syncthreads();
    }

    float4 b4 = *(const float4*)(bias + tcol * 4);
    #pragma unroll
    for (int m = 0; m < 8; ++m) {
        int gr = row0 + trow * 8 + m;
        if (gr >= N) continue;
        float4 o;
        o.x = acc[m][0] + b4.x;
        o.y = acc[m][1] + b4.y;
        o.z = acc[m][2] + b4.z;
        o.w = acc[m][3] + b4.w;
        if (relu) {
            o.x = fmaxf(o.x, 0.f);
            o.y = fmaxf(o.y, 0.f);
            o.z = fmaxf(o.z, 0.f);
            o.w = fmaxf(o.w, 0.f);
        }
        *(float4*)(out + (size_t)gr * D + tcol * 4) = o;
    }
}

// ---------------- launch ----------------

extern "C" void kernel_launch(void* const* d_in, const int* in_sizes, int n_in,
                              void* d_out, int out_size, void* d_ws, size_t ws_size,
                              hipStream_t stream) {
    const float* feats = (const float*)d_in[0];
    const float* ew    = (const float*)d_in[1];
    const float* Wself[3]  = {(const float*)d_in[2], (const float*)d_in[5], (const float*)d_in[8]};
    const float* Wneigh[3] = {(const float*)d_in[3], (const float*)d_in[6], (const float*)d_in[9]};
    const float* bias[3]   = {(const float*)d_in[4], (const float*)d_in[7], (const float*)d_in[10]};
    const int* src = (const int*)d_in[11];
    const int* dst = (const int*)d_in[12];

    int N = in_sizes[0] / D;
    int E = in_sizes[11];

    char* ws = (char*)d_ws;
    size_t p = 0;
    auto align256 = [&]() { p = (p + 255) & ~(size_t)255; };

    // zero region: dsrc, ddst, cnt, fill (contiguous, one memset)
    float* dsrc = (float*)(ws + p); p += (size_t)N * 4;
    float* ddst = (float*)(ws + p); p += (size_t)N * 4;
    int* cnt    = (int*)(ws + p);   p += (size_t)N * 4;
    int* fillc  = (int*)(ws + p);   p += (size_t)N * 4;
    size_t zero_bytes = p;
    align256();
    int* rowp = (int*)(ws + p); p += (size_t)(N + 1) * 4; align256();
    int* tmp  = (int*)(ws + p); p += (size_t)N * 4;        align256();
    int* bsum = (int*)(ws + p); p += 256 * 4;              align256();
    int* boff = (int*)(ws + p); p += 256 * 4;              align256();
    int* csrc   = (int*)(ws + p);   p += (size_t)E * 4;    align256();
    float* cwt  = (float*)(ws + p); p += (size_t)E * 4;    align256();
    float* hb0  = (float*)(ws + p); p += (size_t)N * D * 4; align256();
    float* hb1  = (float*)(ws + p); p += (size_t)N * D * 4; align256();
    float* neigh = (float*)(ws + p); p += (size_t)N * D * 4; align256();
    (void)ws_size; (void)n_in; (void)out_size;

    hipMemsetAsync(ws, 0, zero_bytes, stream);

    int eb = (E + 255) / 256;
    int nb = (N + 255) / 256;  // 196 for N=50000 (must be <= 256)

    deg_kernel<<<eb, 256, 0, stream>>>(src, dst, ew, dsrc, ddst, cnt, E);
    scanA<<<nb, 256, 0, stream>>>(cnt, tmp, bsum, N);
    scanB<<<1, 256, 0, stream>>>(bsum, boff, nb);
    scanC<<<nb, 256, 0, stream>>>(tmp, boff, rowp, N);
    fill_kernel<<<eb, 256, 0, stream>>>(src, dst, ew, dsrc, ddst, cnt, rowp, fillc, csrc, cwt, E);

    const float* hin = feats;
    float* houts[3] = {hb0, hb1, (float*)d_out};
    for (int L = 0; L < 3; ++L) {
        aggregate<<<(N + 3) / 4, 256, 0, stream>>>(hin, rowp, csrc, cwt, neigh, N);
        sage_gemm<<<(N + BM - 1) / BM, 256, 0, stream>>>(hin, neigh, Wself[L], Wneigh[L],
                                                         bias[L], houts[L], N, (L < 2) ? 1 : 0);
        hin = houts[L];
    }
}

// Round 2
// 491.635 us; speedup vs baseline: 1.0656x; 1.0656x over previous
//
#include <hip/hip_runtime.h>
#include <hip/hip_bf16.h>

#define D 128
#define KC 8   // privatized copies for dst-side counters (cnt, fill)
#define KS 8   // privatized copies for src-side weighted degree

// ---------------- preprocessing ----------------

// 2 atomics/edge (was 3), each spread over K copies to cut per-cacheline serialization
__global__ void deg_kernel(const int* __restrict__ src, const int* __restrict__ dst,
                           const float* __restrict__ ew,
                           int* __restrict__ cnt_k, float* __restrict__ dsrc_k,
                           int E, int N) {
    int e = blockIdx.x * 256 + threadIdx.x;
    if (e >= E) return;
    int kc = e & (KC - 1);
    int ks = e & (KS - 1);
    atomicAdd(&cnt_k[kc * N + dst[e]], 1);
    atomicAdd(&dsrc_k[ks * N + src[e]], ew[e]);
}

// inclusive block scan of sum_k cnt_k -> tmp, block totals -> bsum
__global__ void scanA(const int* __restrict__ cnt_k, int* __restrict__ tmp,
                      int* __restrict__ bsum, int N) {
    __shared__ int s[256];
    int tid = threadIdx.x;
    int i = blockIdx.x * 256 + tid;
    int v = 0;
    if (i < N) {
        #pragma unroll
        for (int k = 0; k < KC; ++k) v += cnt_k[k * N + i];
    }
    s[tid] = v;
    __syncthreads();
    #pragma unroll
    for (int off = 1; off < 256; off <<= 1) {
        int t = (tid >= off) ? s[tid - off] : 0;
        __syncthreads();
        s[tid] += t;
        __syncthreads();
    }
    if (i < N) tmp[i] = s[tid];
    if (tid == 255) bsum[blockIdx.x] = s[255];
}

// exclusive scan of block sums (nb <= 256)
__global__ void scanB(const int* __restrict__ bsum, int* __restrict__ boff, int nb) {
    __shared__ int s[256];
    int tid = threadIdx.x;
    int v = (tid < nb) ? bsum[tid] : 0;
    s[tid] = v;
    __syncthreads();
    #pragma unroll
    for (int off = 1; off < 256; off <<= 1) {
        int t = (tid >= off) ? s[tid - off] : 0;
        __syncthreads();
        s[tid] += t;
        __syncthreads();
    }
    if (tid < nb) boff[tid] = s[tid] - v;  // exclusive
}

__global__ void scanC(const int* __restrict__ tmp, const int* __restrict__ boff,
                      int* __restrict__ rowp, int N) {
    int i = blockIdx.x * 256 + threadIdx.x;
    if (i < N) rowp[i + 1] = tmp[i] + boff[blockIdx.x];
    if (i == 0) rowp[0] = 0;
}

// per-node sub-range bases so fill can use K spread counters
__global__ void suboff_kernel(const int* __restrict__ cnt_k, const int* __restrict__ rowp,
                              int* __restrict__ sub_off, int N) {
    int d = blockIdx.x * 256 + threadIdx.x;
    if (d >= N) return;
    int base = rowp[d];
    #pragma unroll
    for (int k = 0; k < KC; ++k) {
        sub_off[k * N + d] = base;
        base += cnt_k[k * N + d];
    }
}

// scatter edges into CSR-by-dst; entry = {src, raw ew} packed 8B
__global__ void fill_kernel(const int* __restrict__ src, const int* __restrict__ dst,
                            const float* __restrict__ ew,
                            const int* __restrict__ sub_off, int* __restrict__ fill_k,
                            int2* __restrict__ csr, int E, int N) {
    int e = blockIdx.x * 256 + threadIdx.x;
    if (e >= E) return;
    int d = dst[e];
    int k = e & (KC - 1);
    int p = sub_off[k * N + d] + atomicAdd(&fill_k[k * N + d], 1);
    csr[p] = make_int2(src[e], __float_as_int(ew[e]));
}

// per-node scales: rs[v] = 1/sqrt(dsrc), os[v] = 1/(sqrt(ddst)*cnt)
// (clamps in reference never bind: self-loop => deg >= 0.05, cnt >= 1)
__global__ void nodeinfo(const int2* __restrict__ csr, const int* __restrict__ rowp,
                         const float* __restrict__ dsrc_k,
                         float* __restrict__ rs, float* __restrict__ os, int N) {
    int wave = (blockIdx.x * blockDim.x + threadIdx.x) >> 6;
    int lane = threadIdx.x & 63;
    if (wave >= N) return;
    int beg = rowp[wave], end = rowp[wave + 1];
    float wsum = 0.f;
    for (int i = beg + lane; i < end; i += 64) wsum += __int_as_float(csr[i].y);
    #pragma unroll
    for (int off = 32; off; off >>= 1) wsum += __shfl_down(wsum, off);
    float ds = (lane < KS) ? dsrc_k[lane * N + wave] : 0.f;
    #pragma unroll
    for (int off = KS / 2; off; off >>= 1) ds += __shfl_down(ds, off);
    if (lane == 0) {
        rs[wave] = rsqrtf(ds);
        os[wave] = rsqrtf(wsum) / (float)(end - beg);
    }
}

// ---------------- per-layer: aggregate (one wave per node) ----------------

__global__ void aggregate(const float* __restrict__ h, const int* __restrict__ rowp,
                          const int2* __restrict__ csr, const float* __restrict__ rs,
                          const float* __restrict__ os,
                          float* __restrict__ neigh, int N) {
    int wave = (blockIdx.x * blockDim.x + threadIdx.x) >> 6;
    int lane = threadIdx.x & 63;
    if (wave >= N) return;
    int beg = rowp[wave], end = rowp[wave + 1];
    const float2* h2 = (const float2*)h;
    float2 a0 = {0.f, 0.f}, a1 = {0.f, 0.f}, a2 = {0.f, 0.f}, a3 = {0.f, 0.f};
    int i = beg;
    for (; i + 4 <= end; i += 4) {
        int2 e0 = csr[i], e1 = csr[i + 1], e2 = csr[i + 2], e3 = csr[i + 3];
        float w0 = __int_as_float(e0.y) * rs[e0.x];
        float w1 = __int_as_float(e1.y) * rs[e1.x];
        float w2 = __int_as_float(e2.y) * rs[e2.x];
        float w3 = __int_as_float(e3.y) * rs[e3.x];
        float2 x0 = h2[(size_t)e0.x * 64 + lane];
        float2 x1 = h2[(size_t)e1.x * 64 + lane];
        float2 x2 = h2[(size_t)e2.x * 64 + lane];
        float2 x3 = h2[(size_t)e3.x * 64 + lane];
        a0.x += w0 * x0.x; a0.y += w0 * x0.y;
        a1.x += w1 * x1.x; a1.y += w1 * x1.y;
        a2.x += w2 * x2.x; a2.y += w2 * x2.y;
        a3.x += w3 * x3.x; a3.y += w3 * x3.y;
    }
    for (; i < end; ++i) {
        int2 e0 = csr[i];
        float w0 = __int_as_float(e0.y) * rs[e0.x];
        float2 x0 = h2[(size_t)e0.x * 64 + lane];
        a0.x += w0 * x0.x; a0.y += w0 * x0.y;
    }
    float o = os[wave];
    float2 r;
    r.x = o * ((a0.x + a1.x) + (a2.x + a3.x));
    r.y = o * ((a0.y + a1.y) + (a2.y + a3.y));
    ((float2*)neigh)[(size_t)wave * 64 + lane] = r;
}

// ---------------- per-layer: fused dual GEMM + bias + relu ----------------
// out[v][d] = sum_k h[v][k]*W1[k][d] + sum_k neigh[v][k]*W2[k][d] + b[d]

#define BM 64
#define BK 32
#define ASTRIDE 68  // 272B row stride: 16B-aligned for b128 reads, breaks pow2 bank stride

__global__ __launch_bounds__(256) void sage_gemm(
    const float* __restrict__ A1, const float* __restrict__ A2,
    const float* __restrict__ W1, const float* __restrict__ W2,
    const float* __restrict__ bias, float* __restrict__ out, int N, int relu) {
    __shared__ float As[BK][ASTRIDE];
    __shared__ float Ws[BK][D];

    int tid = threadIdx.x;
    int row0 = blockIdx.x * BM;
    int tcol = tid & 31;
    int trow = tid >> 5;

    float acc[8][4] = {};

    for (int kc = 0; kc < 8; ++kc) {
        const float* A = (kc < 4) ? A1 : A2;
        const float* W = (kc < 4) ? W1 : W2;
        int kbase = (kc & 3) * BK;

        {
            int r = tid >> 3;
            int c4 = (tid & 7) * 4;
            #pragma unroll
            for (int half = 0; half < 2; ++half) {
                int rr = r + half * 32;
                int gr = row0 + rr;
                float4 v = {0.f, 0.f, 0.f, 0.f};
                if (gr < N) v = *(const float4*)(A + (size_t)gr * D + kbase + c4);
                As[c4 + 0][rr] = v.x;
                As[c4 + 1][rr] = v.y;
                As[c4 + 2][rr] = v.z;
                As[c4 + 3][rr] = v.w;
            }
        }
        {
            int c4 = (tid & 31) * 4;
            int kk0 = tid >> 5;
            #pragma unroll
            for (int i = 0; i < 4; ++i) {
                int kk = kk0 + i * 8;
                float4 v = *(const float4*)(W + (size_t)(kbase + kk) * D + c4);
                *(float4*)&Ws[kk][c4] = v;
            }
        }
        __syncthreads();

        #pragma unroll
        for (int k = 0; k < BK; ++k) {
            float4 a0 = *(const float4*)&As[k][trow * 8];
            float4 a1 = *(const float4*)&As[k][trow * 8 + 4];
            float4 w = *(const float4*)&Ws[k][tcol * 4];
            float am[8] = {a0.x, a0.y, a0.z, a0.w, a1.x, a1.y, a1.z, a1.w};
            float wn[4] = {w.x, w.y, w.z, w.w};
            #pragma unroll
            for (int m = 0; m < 8; ++m)
                #pragma unroll
                for (int n = 0; n < 4; ++n)
                    acc[m][n] += am[m] * wn[n];
        }
        __syncthreads();
    }

    float4 b4 = *(const float4*)(bias + tcol * 4);
    #pragma unroll
    for (int m = 0; m < 8; ++m) {
        int gr = row0 + trow * 8 + m;
        if (gr >= N) continue;
        float4 o;
        o.x = acc[m][0] + b4.x;
        o.y = acc[m][1] + b4.y;
        o.z = acc[m][2] + b4.z;
        o.w = acc[m][3] + b4.w;
        if (relu) {
            o.x = fmaxf(o.x, 0.f);
            o.y = fmaxf(o.y, 0.f);
            o.z = fmaxf(o.z, 0.f);
            o.w = fmaxf(o.w, 0.f);
        }
        *(float4*)(out + (size_t)gr * D + tcol * 4) = o;
    }
}

// ---------------- launch ----------------

extern "C" void kernel_launch(void* const* d_in, const int* in_sizes, int n_in,
                              void* d_out, int out_size, void* d_ws, size_t ws_size,
                              hipStream_t stream) {
    const float* feats = (const float*)d_in[0];
    const float* ew    = (const float*)d_in[1];
    const float* Wself[3]  = {(const float*)d_in[2], (const float*)d_in[5], (const float*)d_in[8]};
    const float* Wneigh[3] = {(const float*)d_in[3], (const float*)d_in[6], (const float*)d_in[9]};
    const float* bias[3]   = {(const float*)d_in[4], (const float*)d_in[7], (const float*)d_in[10]};
    const int* src = (const int*)d_in[11];
    const int* dst = (const int*)d_in[12];

    int N = in_sizes[0] / D;
    int E = in_sizes[11];

    char* ws = (char*)d_ws;
    size_t p = 0;
    auto align256 = [&]() { p = (p + 255) & ~(size_t)255; };

    // zero region 1: cnt_k + dsrc_k (contiguous memset)
    int*   cnt_k  = (int*)(ws + p);   p += (size_t)KC * N * 4;
    float* dsrc_k = (float*)(ws + p); p += (size_t)KS * N * 4;
    size_t zero1_bytes = p;
    align256();
    int* rowp    = (int*)(ws + p); p += (size_t)(N + 1) * 4; align256();
    int* tmp     = (int*)(ws + p); p += (size_t)N * 4;       align256();
    int* bsum    = (int*)(ws + p); p += 256 * 4;             align256();
    int* boff    = (int*)(ws + p); p += 256 * 4;             align256();
    int* sub_off = (int*)(ws + p); p += (size_t)KC * N * 4;  align256();
    int2* csr    = (int2*)(ws + p);  p += (size_t)E * 8;     align256();
    float* rs    = (float*)(ws + p); p += (size_t)N * 4;     align256();
    float* osb   = (float*)(ws + p); p += (size_t)N * 4;     align256();
    float* hb1   = (float*)(ws + p); p += (size_t)N * D * 4; align256();
    float* neigh = (float*)(ws + p); p += (size_t)N * D * 4; align256();
    (void)ws_size; (void)n_in; (void)out_size;

    hipMemsetAsync(ws, 0, zero1_bytes, stream);

    int eb = (E + 255) / 256;
    int nb = (N + 255) / 256;  // 196 for N=50000 (must be <= 256)

    deg_kernel<<<eb, 256, 0, stream>>>(src, dst, ew, cnt_k, dsrc_k, E, N);
    scanA<<<nb, 256, 0, stream>>>(cnt_k, tmp, bsum, N);
    scanB<<<1, 256, 0, stream>>>(bsum, boff, nb);
    scanC<<<nb, 256, 0, stream>>>(tmp, boff, rowp, N);
    suboff_kernel<<<nb, 256, 0, stream>>>(cnt_k, rowp, sub_off, N);
    // reuse cnt_k region as fill counters (re-zero after suboff consumed it)
    int* fill_k = cnt_k;
    hipMemsetAsync(fill_k, 0, (size_t)KC * N * 4, stream);
    fill_kernel<<<eb, 256, 0, stream>>>(src, dst, ew, sub_off, fill_k, csr, E, N);
    nodeinfo<<<(N + 3) / 4, 256, 0, stream>>>(csr, rowp, dsrc_k, rs, osb, N);

    // h buffers: layer0 -> d_out, layer1 -> hb1, layer2 -> d_out (final)
    const float* hin = feats;
    float* houts[3] = {(float*)d_out, hb1, (float*)d_out};
    for (int L = 0; L < 3; ++L) {
        aggregate<<<(N + 3) / 4, 256, 0, stream>>>(hin, rowp, csr, rs, osb, neigh, N);
        sage_gemm<<<(N + BM - 1) / BM, 256, 0, stream>>>(hin, neigh, Wself[L], Wneigh[L],
                                                         bias[L], houts[L], N, (L < 2) ? 1 : 0);
        hin = houts[L];
    }
}

// Round 3
// 393.502 us; speedup vs baseline: 1.3314x; 1.2494x over previous
//
#include <hip/hip_runtime.h>
#include <hip/hip_bf16.h>

#define D 128
#define BS 256
#define CHUNK 4096   // edges per hist/partition block

// ---------------- preprocessing (no global atomics) ----------------

// per-block bucket histograms: dst>>8 (CSR key) and src>>8 (degree key)
__global__ void hist_kernel(const int* __restrict__ src, const int* __restrict__ dst,
                            int* __restrict__ H, int E, int EB, int NB) {
    __shared__ int hD[256], hS[256];
    int tid = threadIdx.x, blk = blockIdx.x;
    hD[tid] = 0; hS[tid] = 0;
    __syncthreads();
    int e0 = blk * CHUNK;
    int e1 = e0 + CHUNK < E ? e0 + CHUNK : E;
    for (int e = e0 + tid; e < e1; e += BS) {
        atomicAdd(&hD[dst[e] >> 8], 1);
        atomicAdd(&hS[src[e] >> 8], 1);
    }
    __syncthreads();
    if (tid < NB) {
        H[tid * EB + blk] = hD[tid];
        H[NB * EB + tid * EB + blk] = hS[tid];
    }
}

// inclusive 512-block scan
__global__ void scanA(const int* __restrict__ H, int* __restrict__ tmp,
                      int* __restrict__ bsum, int L) {
    __shared__ int s[512];
    int tid = threadIdx.x;
    int i = blockIdx.x * 512 + tid;
    int v = (i < L) ? H[i] : 0;
    s[tid] = v;
    __syncthreads();
    for (int off = 1; off < 512; off <<= 1) {
        int t = (tid >= off) ? s[tid - off] : 0;
        __syncthreads();
        s[tid] += t;
        __syncthreads();
    }
    if (i < L) tmp[i] = s[tid];
    if (tid == 511) bsum[blockIdx.x] = s[511];
}

// exclusive scan of block totals (nb <= 512)
__global__ void scanB(const int* __restrict__ bsum, int* __restrict__ boff, int nb) {
    __shared__ int s[512];
    int tid = threadIdx.x;
    int v = (tid < nb) ? bsum[tid] : 0;
    s[tid] = v;
    __syncthreads();
    for (int off = 1; off < 512; off <<= 1) {
        int t = (tid >= off) ? s[tid - off] : 0;
        __syncthreads();
        s[tid] += t;
        __syncthreads();
    }
    if (tid < nb) boff[tid] = s[tid] - v;
}

// H <- global EXCLUSIVE scan, in place
__global__ void scanC(int* __restrict__ H, const int* __restrict__ tmp,
                      const int* __restrict__ boff, int L) {
    int i = blockIdx.x * 512 + threadIdx.x;
    if (i < L) H[i] = tmp[i] + boff[blockIdx.x] - H[i];
}

// scatter edges into the two binned buffers at exact scanned positions
// bufD entry: {(dst&255)<<16 | src, ew}   (requires N <= 65536)
// bufS entry: {src, ew}
__global__ void partition_kernel(const int* __restrict__ src, const int* __restrict__ dst,
                                 const float* __restrict__ ew, const int* __restrict__ H,
                                 int2* __restrict__ bufD, int2* __restrict__ bufS,
                                 int E, int EB, int NB) {
    __shared__ int curD[256], curS[256];
    int tid = threadIdx.x, blk = blockIdx.x;
    if (tid < NB) {
        curD[tid] = H[tid * EB + blk];
        curS[tid] = H[NB * EB + tid * EB + blk] - E;
    }
    __syncthreads();
    int e0 = blk * CHUNK;
    int e1 = e0 + CHUNK < E ? e0 + CHUNK : E;
    for (int e = e0 + tid; e < e1; e += BS) {
        int s = src[e], d = dst[e];
        int w = __float_as_int(ew[e]);
        int pD = atomicAdd(&curD[d >> 8], 1);
        bufD[pD] = make_int2(((d & 255) << 16) | s, w);
        int pS = atomicAdd(&curS[s >> 8], 1);
        bufS[pS] = make_int2(s, w);
    }
}

// per src-bucket: weighted out-degree -> rs = 1/sqrt(dsrc)
// (reference clamps never bind: self-loops guarantee deg >= 0.05, cnt >= 1)
__global__ void srcdeg_kernel(const int2* __restrict__ bufS, const int* __restrict__ H,
                              float* __restrict__ rs, int E, int EB, int NB, int N) {
    __shared__ float acc[256];
    int tid = threadIdx.x, b = blockIdx.x;
    acc[tid] = 0.f;
    __syncthreads();
    int base = H[NB * EB + b * EB] - E;
    int end = (b + 1 < NB) ? H[NB * EB + (b + 1) * EB] - E : E;
    for (int i = base + tid; i < end; i += BS) {
        int2 v = bufS[i];
        atomicAdd(&acc[v.x & 255], __int_as_float(v.y));
    }
    __syncthreads();
    int node = (b << 8) + tid;
    if (node < N) rs[node] = rsqrtf(acc[tid]);
}

// per dst-bucket: counting sort to CSR, rowp, and fully-folded edge weight
// w_final = ew * rs[src] * rsqrt(ddst) / in_cnt  (both-norm + mean folded)
__global__ void csr_kernel(const int2* __restrict__ bufD, const int* __restrict__ H,
                           const float* __restrict__ rs, int* __restrict__ rowp,
                           int2* __restrict__ csr, int E, int EB, int NB, int N) {
    __shared__ int lcnt[256];
    __shared__ float lw[256];
    __shared__ int sc[256];
    int tid = threadIdx.x, b = blockIdx.x;
    lcnt[tid] = 0; lw[tid] = 0.f;
    __syncthreads();
    int base = H[b * EB];
    int end = (b + 1 < NB) ? H[(b + 1) * EB] : E;
    for (int i = base + tid; i < end; i += BS) {
        int2 v = bufD[i];
        int l = v.x >> 16;
        atomicAdd(&lcnt[l], 1);
        atomicAdd(&lw[l], __int_as_float(v.y));
    }
    __syncthreads();
    int myc = lcnt[tid];
    float myw = lw[tid];
    sc[tid] = myc;
    __syncthreads();
    for (int off = 1; off < 256; off <<= 1) {
        int t = (tid >= off) ? sc[tid - off] : 0;
        __syncthreads();
        sc[tid] += t;
        __syncthreads();
    }
    int lbase = base + sc[tid] - myc;  // exclusive within bucket + global base
    int node = (b << 8) + tid;
    if (node < N) rowp[node] = lbase;
    if (b == 0 && tid == 0) rowp[N] = E;
    // reuse: lcnt -> write cursor, lw -> per-node os scale
    lcnt[tid] = lbase;
    lw[tid] = (myc > 0) ? rsqrtf(myw) / (float)myc : 0.f;
    __syncthreads();
    for (int i = base + tid; i < end; i += BS) {
        int2 v = bufD[i];
        int l = v.x >> 16;
        int s = v.x & 0xFFFF;
        float w = __int_as_float(v.y) * rs[s] * lw[l];
        int p = atomicAdd(&lcnt[l], 1);
        csr[p] = make_int2(s, __float_as_int(w));
    }
}

// ---------------- per-layer: aggregate (one wave per node) ----------------

__global__ void aggregate(const float* __restrict__ h, const int* __restrict__ rowp,
                          const int2* __restrict__ csr, float* __restrict__ neigh, int N) {
    int wave = (blockIdx.x * blockDim.x + threadIdx.x) >> 6;
    int lane = threadIdx.x & 63;
    if (wave >= N) return;
    int beg = rowp[wave], end = rowp[wave + 1];
    const float2* h2 = (const float2*)h;
    float2 a0 = {0.f, 0.f}, a1 = {0.f, 0.f}, a2 = {0.f, 0.f}, a3 = {0.f, 0.f};
    int i = beg;
    for (; i + 4 <= end; i += 4) {
        int2 e0 = csr[i], e1 = csr[i + 1], e2 = csr[i + 2], e3 = csr[i + 3];
        float w0 = __int_as_float(e0.y);
        float w1 = __int_as_float(e1.y);
        float w2 = __int_as_float(e2.y);
        float w3 = __int_as_float(e3.y);
        float2 x0 = h2[(size_t)e0.x * 64 + lane];
        float2 x1 = h2[(size_t)e1.x * 64 + lane];
        float2 x2 = h2[(size_t)e2.x * 64 + lane];
        float2 x3 = h2[(size_t)e3.x * 64 + lane];
        a0.x += w0 * x0.x; a0.y += w0 * x0.y;
        a1.x += w1 * x1.x; a1.y += w1 * x1.y;
        a2.x += w2 * x2.x; a2.y += w2 * x2.y;
        a3.x += w3 * x3.x; a3.y += w3 * x3.y;
    }
    for (; i < end; ++i) {
        int2 e0 = csr[i];
        float w0 = __int_as_float(e0.y);
        float2 x0 = h2[(size_t)e0.x * 64 + lane];
        a0.x += w0 * x0.x; a0.y += w0 * x0.y;
    }
    float2 r;
    r.x = (a0.x + a1.x) + (a2.x + a3.x);
    r.y = (a0.y + a1.y) + (a2.y + a3.y);
    ((float2*)neigh)[(size_t)wave * 64 + lane] = r;
}

// ---------------- per-layer: fused dual GEMM + bias + relu ----------------

#define BM 64
#define BK 32
#define ASTRIDE 68  // 272B row stride: 16B-aligned b128 reads, breaks pow2 bank stride

__global__ __launch_bounds__(256) void sage_gemm(
    const float* __restrict__ A1, const float* __restrict__ A2,
    const float* __restrict__ W1, const float* __restrict__ W2,
    const float* __restrict__ bias, float* __restrict__ out, int N, int relu) {
    __shared__ float As[BK][ASTRIDE];
    __shared__ float Ws[BK][D];

    int tid = threadIdx.x;
    int row0 = blockIdx.x * BM;
    int tcol = tid & 31;
    int trow = tid >> 5;

    float acc[8][4] = {};

    for (int kc = 0; kc < 8; ++kc) {
        const float* A = (kc < 4) ? A1 : A2;
        const float* W = (kc < 4) ? W1 : W2;
        int kbase = (kc & 3) * BK;

        {
            int r = tid >> 3;
            int c4 = (tid & 7) * 4;
            #pragma unroll
            for (int half = 0; half < 2; ++half) {
                int rr = r + half * 32;
                int gr = row0 + rr;
                float4 v = {0.f, 0.f, 0.f, 0.f};
                if (gr < N) v = *(const float4*)(A + (size_t)gr * D + kbase + c4);
                As[c4 + 0][rr] = v.x;
                As[c4 + 1][rr] = v.y;
                As[c4 + 2][rr] = v.z;
                As[c4 + 3][rr] = v.w;
            }
        }
        {
            int c4 = (tid & 31) * 4;
            int kk0 = tid >> 5;
            #pragma unroll
            for (int i = 0; i < 4; ++i) {
                int kk = kk0 + i * 8;
                float4 v = *(const float4*)(W + (size_t)(kbase + kk) * D + c4);
                *(float4*)&Ws[kk][c4] = v;
            }
        }
        __syncthreads();

        #pragma unroll
        for (int k = 0; k < BK; ++k) {
            float4 a0 = *(const float4*)&As[k][trow * 8];
            float4 a1 = *(const float4*)&As[k][trow * 8 + 4];
            float4 w = *(const float4*)&Ws[k][tcol * 4];
            float am[8] = {a0.x, a0.y, a0.z, a0.w, a1.x, a1.y, a1.z, a1.w};
            float wn[4] = {w.x, w.y, w.z, w.w};
            #pragma unroll
            for (int m = 0; m < 8; ++m)
                #pragma unroll
                for (int n = 0; n < 4; ++n)
                    acc[m][n] += am[m] * wn[n];
        }
        __syncthreads();
    }

    float4 b4 = *(const float4*)(bias + tcol * 4);
    #pragma unroll
    for (int m = 0; m < 8; ++m) {
        int gr = row0 + trow * 8 + m;
        if (gr >= N) continue;
        float4 o;
        o.x = acc[m][0] + b4.x;
        o.y = acc[m][1] + b4.y;
        o.z = acc[m][2] + b4.z;
        o.w = acc[m][3] + b4.w;
        if (relu) {
            o.x = fmaxf(o.x, 0.f);
            o.y = fmaxf(o.y, 0.f);
            o.z = fmaxf(o.z, 0.f);
            o.w = fmaxf(o.w, 0.f);
        }
        *(float4*)(out + (size_t)gr * D + tcol * 4) = o;
    }
}

// ---------------- launch ----------------

extern "C" void kernel_launch(void* const* d_in, const int* in_sizes, int n_in,
                              void* d_out, int out_size, void* d_ws, size_t ws_size,
                              hipStream_t stream) {
    const float* feats = (const float*)d_in[0];
    const float* ew    = (const float*)d_in[1];
    const float* Wself[3]  = {(const float*)d_in[2], (const float*)d_in[5], (const float*)d_in[8]};
    const float* Wneigh[3] = {(const float*)d_in[3], (const float*)d_in[6], (const float*)d_in[9]};
    const float* bias[3]   = {(const float*)d_in[4], (const float*)d_in[7], (const float*)d_in[10]};
    const int* src = (const int*)d_in[11];
    const int* dst = (const int*)d_in[12];

    int N = in_sizes[0] / D;     // 50000 (requires <= 65536 for 16-bit src pack)
    int E = in_sizes[11];        // 850000
    int NB = (N + 255) >> 8;     // 196 buckets
    int EB = (E + CHUNK - 1) / CHUNK;  // 208 edge blocks
    int L = 2 * NB * EB;         // 81536 histogram entries
    int sblocks = (L + 511) / 512;     // 160 (<= 512 for scanB)

    char* ws = (char*)d_ws;
    size_t p = 0;
    auto align256 = [&]() { p = (p + 255) & ~(size_t)255; };

    int* H    = (int*)(ws + p); p += (size_t)L * 4;        align256();
    int* tmp  = (int*)(ws + p); p += (size_t)L * 4;        align256();
    int* bsum = (int*)(ws + p); p += 512 * 4;              align256();
    int* boff = (int*)(ws + p); p += 512 * 4;              align256();
    int2* bufD = (int2*)(ws + p); p += (size_t)E * 8;      align256();
    int2* bufS = (int2*)(ws + p); p += (size_t)E * 8;      align256();
    int2* csr  = bufS;  // bufS fully consumed (srcdeg) before csr is written
    int* rowp  = (int*)(ws + p);   p += (size_t)(N + 1) * 4; align256();
    float* rs  = (float*)(ws + p); p += (size_t)N * 4;       align256();
    float* hb1 = (float*)(ws + p); p += (size_t)N * D * 4;   align256();
    float* neigh = (float*)(ws + p); p += (size_t)N * D * 4; align256();
    (void)ws_size; (void)n_in; (void)out_size;

    hist_kernel<<<EB, BS, 0, stream>>>(src, dst, H, E, EB, NB);
    scanA<<<sblocks, 512, 0, stream>>>(H, tmp, bsum, L);
    scanB<<<1, 512, 0, stream>>>(bsum, boff, sblocks);
    scanC<<<sblocks, 512, 0, stream>>>(H, tmp, boff, L);
    partition_kernel<<<EB, BS, 0, stream>>>(src, dst, ew, H, bufD, bufS, E, EB, NB);
    srcdeg_kernel<<<NB, BS, 0, stream>>>(bufS, H, rs, E, EB, NB, N);
    csr_kernel<<<NB, BS, 0, stream>>>(bufD, H, rs, rowp, csr, E, EB, NB, N);

    // h buffers: layer0 -> d_out, layer1 -> hb1, layer2 -> d_out (final)
    const float* hin = feats;
    float* houts[3] = {(float*)d_out, hb1, (float*)d_out};
    for (int Lr = 0; Lr < 3; ++Lr) {
        aggregate<<<(N + 3) / 4, 256, 0, stream>>>(hin, rowp, csr, neigh, N);
        sage_gemm<<<(N + BM - 1) / BM, 256, 0, stream>>>(hin, neigh, Wself[Lr], Wneigh[Lr],
                                                         bias[Lr], houts[Lr], N, (Lr < 2) ? 1 : 0);
        hin = houts[Lr];
    }
}

// Round 4
// 383.164 us; speedup vs baseline: 1.3673x; 1.0270x over previous
//
#include <hip/hip_runtime.h>
#include <hip/hip_bf16.h>

#define D 128
#define BS 256
#define CHUNK 4096   // edges per hist/partition block

// ---------------- preprocessing (no global atomics) ----------------

// per-block bucket histograms: dst>>8 (CSR key) and src>>8 (degree key)
__global__ void hist_kernel(const int* __restrict__ src, const int* __restrict__ dst,
                            int* __restrict__ H, int E, int EB, int NB) {
    __shared__ int hD[256], hS[256];
    int tid = threadIdx.x, blk = blockIdx.x;
    hD[tid] = 0; hS[tid] = 0;
    __syncthreads();
    int e0 = blk * CHUNK;
    int e1 = e0 + CHUNK < E ? e0 + CHUNK : E;
    for (int e = e0 + tid; e < e1; e += BS) {
        atomicAdd(&hD[dst[e] >> 8], 1);
        atomicAdd(&hS[src[e] >> 8], 1);
    }
    __syncthreads();
    if (tid < NB) {
        H[tid * EB + blk] = hD[tid];
        H[NB * EB + tid * EB + blk] = hS[tid];
    }
}

// inclusive 512-block scan
__global__ void scanA(const int* __restrict__ H, int* __restrict__ tmp,
                      int* __restrict__ bsum, int L) {
    __shared__ int s[512];
    int tid = threadIdx.x;
    int i = blockIdx.x * 512 + tid;
    int v = (i < L) ? H[i] : 0;
    s[tid] = v;
    __syncthreads();
    for (int off = 1; off < 512; off <<= 1) {
        int t = (tid >= off) ? s[tid - off] : 0;
        __syncthreads();
        s[tid] += t;
        __syncthreads();
    }
    if (i < L) tmp[i] = s[tid];
    if (tid == 511) bsum[blockIdx.x] = s[511];
}

// exclusive scan of block totals (nb <= 512)
__global__ void scanB(const int* __restrict__ bsum, int* __restrict__ boff, int nb) {
    __shared__ int s[512];
    int tid = threadIdx.x;
    int v = (tid < nb) ? bsum[tid] : 0;
    s[tid] = v;
    __syncthreads();
    for (int off = 1; off < 512; off <<= 1) {
        int t = (tid >= off) ? s[tid - off] : 0;
        __syncthreads();
        s[tid] += t;
        __syncthreads();
    }
    if (tid < nb) boff[tid] = s[tid] - v;
}

// H <- global EXCLUSIVE scan, in place
__global__ void scanC(int* __restrict__ H, const int* __restrict__ tmp,
                      const int* __restrict__ boff, int L) {
    int i = blockIdx.x * 512 + threadIdx.x;
    if (i < L) H[i] = tmp[i] + boff[blockIdx.x] - H[i];
}

// scatter edges into the two binned buffers at exact scanned positions
// bufD entry: {(dst&255)<<16 | src, ew}   (requires N <= 65536)
// bufS entry: {src, ew}
__global__ void partition_kernel(const int* __restrict__ src, const int* __restrict__ dst,
                                 const float* __restrict__ ew, const int* __restrict__ H,
                                 int2* __restrict__ bufD, int2* __restrict__ bufS,
                                 int E, int EB, int NB) {
    __shared__ int curD[256], curS[256];
    int tid = threadIdx.x, blk = blockIdx.x;
    if (tid < NB) {
        curD[tid] = H[tid * EB + blk];
        curS[tid] = H[NB * EB + tid * EB + blk] - E;
    }
    __syncthreads();
    int e0 = blk * CHUNK;
    int e1 = e0 + CHUNK < E ? e0 + CHUNK : E;
    for (int e = e0 + tid; e < e1; e += BS) {
        int s = src[e], d = dst[e];
        int w = __float_as_int(ew[e]);
        int pD = atomicAdd(&curD[d >> 8], 1);
        bufD[pD] = make_int2(((d & 255) << 16) | s, w);
        int pS = atomicAdd(&curS[s >> 8], 1);
        bufS[pS] = make_int2(s, w);
    }
}

// per src-bucket: weighted out-degree -> rs = 1/sqrt(dsrc)
// (reference clamps never bind: self-loops guarantee deg >= 0.05, cnt >= 1)
__global__ void srcdeg_kernel(const int2* __restrict__ bufS, const int* __restrict__ H,
                              float* __restrict__ rs, int E, int EB, int NB, int N) {
    __shared__ float acc[256];
    int tid = threadIdx.x, b = blockIdx.x;
    acc[tid] = 0.f;
    __syncthreads();
    int base = H[NB * EB + b * EB] - E;
    int end = (b + 1 < NB) ? H[NB * EB + (b + 1) * EB] - E : E;
    for (int i = base + tid; i < end; i += BS) {
        int2 v = bufS[i];
        atomicAdd(&acc[v.x & 255], __int_as_float(v.y));
    }
    __syncthreads();
    int node = (b << 8) + tid;
    if (node < N) rs[node] = rsqrtf(acc[tid]);
}

// per dst-bucket: counting sort to CSR, rowp, and fully-folded edge weight
// w_final = ew * rs[src] * rsqrt(ddst) / in_cnt  (both-norm + mean folded)
__global__ void csr_kernel(const int2* __restrict__ bufD, const int* __restrict__ H,
                           const float* __restrict__ rs, int* __restrict__ rowp,
                           int2* __restrict__ csr, int E, int EB, int NB, int N) {
    __shared__ int lcnt[256];
    __shared__ float lw[256];
    __shared__ int sc[256];
    int tid = threadIdx.x, b = blockIdx.x;
    lcnt[tid] = 0; lw[tid] = 0.f;
    __syncthreads();
    int base = H[b * EB];
    int end = (b + 1 < NB) ? H[(b + 1) * EB] : E;
    for (int i = base + tid; i < end; i += BS) {
        int2 v = bufD[i];
        int l = v.x >> 16;
        atomicAdd(&lcnt[l], 1);
        atomicAdd(&lw[l], __int_as_float(v.y));
    }
    __syncthreads();
    int myc = lcnt[tid];
    float myw = lw[tid];
    sc[tid] = myc;
    __syncthreads();
    for (int off = 1; off < 256; off <<= 1) {
        int t = (tid >= off) ? sc[tid - off] : 0;
        __syncthreads();
        sc[tid] += t;
        __syncthreads();
    }
    int lbase = base + sc[tid] - myc;  // exclusive within bucket + global base
    int node = (b << 8) + tid;
    if (node < N) rowp[node] = lbase;
    if (b == 0 && tid == 0) rowp[N] = E;
    // reuse: lcnt -> write cursor, lw -> per-node os scale
    lcnt[tid] = lbase;
    lw[tid] = (myc > 0) ? rsqrtf(myw) / (float)myc : 0.f;
    __syncthreads();
    for (int i = base + tid; i < end; i += BS) {
        int2 v = bufD[i];
        int l = v.x >> 16;
        int s = v.x & 0xFFFF;
        float w = __int_as_float(v.y) * rs[s] * lw[l];
        int p = atomicAdd(&lcnt[l], 1);
        csr[p] = make_int2(s, __float_as_int(w));
    }
}

// ---------------- per-layer: aggregate (one wave per node) ----------------

__global__ void aggregate(const float* __restrict__ h, const int* __restrict__ rowp,
                          const int2* __restrict__ csr, float* __restrict__ neigh, int N) {
    int wave = (blockIdx.x * blockDim.x + threadIdx.x) >> 6;
    int lane = threadIdx.x & 63;
    if (wave >= N) return;
    int beg = rowp[wave], end = rowp[wave + 1];
    const float2* h2 = (const float2*)h;
    float2 a0 = {0.f, 0.f}, a1 = {0.f, 0.f}, a2 = {0.f, 0.f}, a3 = {0.f, 0.f};
    int i = beg;
    for (; i + 4 <= end; i += 4) {
        int2 e0 = csr[i], e1 = csr[i + 1], e2 = csr[i + 2], e3 = csr[i + 3];
        float w0 = __int_as_float(e0.y);
        float w1 = __int_as_float(e1.y);
        float w2 = __int_as_float(e2.y);
        float w3 = __int_as_float(e3.y);
        float2 x0 = h2[(size_t)e0.x * 64 + lane];
        float2 x1 = h2[(size_t)e1.x * 64 + lane];
        float2 x2 = h2[(size_t)e2.x * 64 + lane];
        float2 x3 = h2[(size_t)e3.x * 64 + lane];
        a0.x += w0 * x0.x; a0.y += w0 * x0.y;
        a1.x += w1 * x1.x; a1.y += w1 * x1.y;
        a2.x += w2 * x2.x; a2.y += w2 * x2.y;
        a3.x += w3 * x3.x; a3.y += w3 * x3.y;
    }
    for (; i < end; ++i) {
        int2 e0 = csr[i];
        float w0 = __int_as_float(e0.y);
        float2 x0 = h2[(size_t)e0.x * 64 + lane];
        a0.x += w0 * x0.x; a0.y += w0 * x0.y;
    }
    float2 r;
    r.x = (a0.x + a1.x) + (a2.x + a3.x);
    r.y = (a0.y + a1.y) + (a2.y + a3.y);
    ((float2*)neigh)[(size_t)wave * 64 + lane] = r;
}

// ---------------- per-layer: fused dual GEMM + bias + relu ----------------
// BM=128, BN=128, BK=32; 256 threads, 8x8 per-thread tile; double-buffered LDS,
// one barrier per chunk. a-frag from transposed As (b128, broadcast, conflict-free),
// w-frag from row-major Ws (b128, 2-way max).

#define GBM 128
#define GBK 32
#define AST 132  // transposed-A row stride (floats): 132*4B = 16B-aligned, mod32 = 4
#define WST 132

__global__ __launch_bounds__(256, 2) void sage_gemm(
    const float* __restrict__ A1, const float* __restrict__ A2,
    const float* __restrict__ W1, const float* __restrict__ W2,
    const float* __restrict__ bias, float* __restrict__ out, int N, int relu) {
    __shared__ float As[2][GBK][AST];
    __shared__ float Ws[2][GBK][WST];

    int tid = threadIdx.x;
    int row0 = blockIdx.x * GBM;
    int tr = tid >> 4;        // 0..15, rows tr*8..+7
    int tc = tid & 15;        // 0..15, cols tc*8..+7

    // staging coords
    int ar = tid >> 1;            // A row 0..127
    int ac = (tid & 1) * 16;      // A col 0 or 16 (16 floats each)
    int wk = tid >> 3;            // W row 0..31
    int wc = (tid & 7) * 16;      // W col 0..112 (16 floats)

    float acc[8][8] = {};
    float ast[16];
    float wst[16];

    // ---- prologue: stage chunk 0 ----
    {
        const float* A = A1;
        const float* W = W1;
        int gr = row0 + ar;
        if (gr < N) {
            const float* p = A + (size_t)gr * D + ac;
            #pragma unroll
            for (int j = 0; j < 4; ++j) {
                float4 v = *(const float4*)(p + 4 * j);
                ast[4 * j + 0] = v.x; ast[4 * j + 1] = v.y;
                ast[4 * j + 2] = v.z; ast[4 * j + 3] = v.w;
            }
        } else {
            #pragma unroll
            for (int j = 0; j < 16; ++j) ast[j] = 0.f;
        }
        const float* q = W + (size_t)wk * D + wc;
        #pragma unroll
        for (int j = 0; j < 4; ++j) {
            float4 v = *(const float4*)(q + 4 * j);
            wst[4 * j + 0] = v.x; wst[4 * j + 1] = v.y;
            wst[4 * j + 2] = v.z; wst[4 * j + 3] = v.w;
        }
        #pragma unroll
        for (int j = 0; j < 16; ++j) As[0][ac + j][ar] = ast[j];
        #pragma unroll
        for (int j = 0; j < 4; ++j)
            *(float4*)&Ws[0][wk][wc + 4 * j] = *(const float4*)&wst[4 * j];
    }
    __syncthreads();

    for (int kc = 0; kc < 8; ++kc) {
        int b = kc & 1;
        // ---- issue global loads for chunk kc+1 ----
        if (kc < 7) {
            int nc = kc + 1;
            const float* A = (nc < 4) ? A1 : A2;
            const float* W = (nc < 4) ? W1 : W2;
            int kbase = (nc & 3) * GBK;
            int gr = row0 + ar;
            if (gr < N) {
                const float* p = A + (size_t)gr * D + kbase + ac;
                #pragma unroll
                for (int j = 0; j < 4; ++j) {
                    float4 v = *(const float4*)(p + 4 * j);
                    ast[4 * j + 0] = v.x; ast[4 * j + 1] = v.y;
                    ast[4 * j + 2] = v.z; ast[4 * j + 3] = v.w;
                }
            } else {
                #pragma unroll
                for (int j = 0; j < 16; ++j) ast[j] = 0.f;
            }
            const float* q = W + (size_t)(kbase + wk) * D + wc;
            #pragma unroll
            for (int j = 0; j < 4; ++j) {
                float4 v = *(const float4*)(q + 4 * j);
                wst[4 * j + 0] = v.x; wst[4 * j + 1] = v.y;
                wst[4 * j + 2] = v.z; wst[4 * j + 3] = v.w;
            }
        }
        // ---- compute on buffer b ----
        #pragma unroll 4
        for (int k = 0; k < GBK; ++k) {
            float4 a0 = *(const float4*)&As[b][k][tr * 8];
            float4 a1 = *(const float4*)&As[b][k][tr * 8 + 4];
            float4 w0 = *(const float4*)&Ws[b][k][tc * 8];
            float4 w1 = *(const float4*)&Ws[b][k][tc * 8 + 4];
            float am[8] = {a0.x, a0.y, a0.z, a0.w, a1.x, a1.y, a1.z, a1.w};
            float wn[8] = {w0.x, w0.y, w0.z, w0.w, w1.x, w1.y, w1.z, w1.w};
            #pragma unroll
            for (int m = 0; m < 8; ++m)
                #pragma unroll
                for (int n = 0; n < 8; ++n)
                    acc[m][n] += am[m] * wn[n];
        }
        // ---- write staged regs to the other buffer ----
        if (kc < 7) {
            int nb = b ^ 1;
            #pragma unroll
            for (int j = 0; j < 16; ++j) As[nb][ac + j][ar] = ast[j];
            #pragma unroll
            for (int j = 0; j < 4; ++j)
                *(float4*)&Ws[nb][wk][wc + 4 * j] = *(const float4*)&wst[4 * j];
        }
        __syncthreads();
    }

    // ---- epilogue ----
    float4 b0 = *(const float4*)(bias + tc * 8);
    float4 b1 = *(const float4*)(bias + tc * 8 + 4);
    #pragma unroll
    for (int m = 0; m < 8; ++m) {
        int gr = row0 + tr * 8 + m;
        if (gr >= N) continue;
        float4 o0, o1;
        o0.x = acc[m][0] + b0.x; o0.y = acc[m][1] + b0.y;
        o0.z = acc[m][2] + b0.z; o0.w = acc[m][3] + b0.w;
        o1.x = acc[m][4] + b1.x; o1.y = acc[m][5] + b1.y;
        o1.z = acc[m][6] + b1.z; o1.w = acc[m][7] + b1.w;
        if (relu) {
            o0.x = fmaxf(o0.x, 0.f); o0.y = fmaxf(o0.y, 0.f);
            o0.z = fmaxf(o0.z, 0.f); o0.w = fmaxf(o0.w, 0.f);
            o1.x = fmaxf(o1.x, 0.f); o1.y = fmaxf(o1.y, 0.f);
            o1.z = fmaxf(o1.z, 0.f); o1.w = fmaxf(o1.w, 0.f);
        }
        *(float4*)(out + (size_t)gr * D + tc * 8) = o0;
        *(float4*)(out + (size_t)gr * D + tc * 8 + 4) = o1;
    }
}

// ---------------- launch ----------------

extern "C" void kernel_launch(void* const* d_in, const int* in_sizes, int n_in,
                              void* d_out, int out_size, void* d_ws, size_t ws_size,
                              hipStream_t stream) {
    const float* feats = (const float*)d_in[0];
    const float* ew    = (const float*)d_in[1];
    const float* Wself[3]  = {(const float*)d_in[2], (const float*)d_in[5], (const float*)d_in[8]};
    const float* Wneigh[3] = {(const float*)d_in[3], (const float*)d_in[6], (const float*)d_in[9]};
    const float* bias[3]   = {(const float*)d_in[4], (const float*)d_in[7], (const float*)d_in[10]};
    const int* src = (const int*)d_in[11];
    const int* dst = (const int*)d_in[12];

    int N = in_sizes[0] / D;     // 50000 (requires <= 65536 for 16-bit src pack)
    int E = in_sizes[11];        // 850000
    int NB = (N + 255) >> 8;     // 196 buckets
    int EB = (E + CHUNK - 1) / CHUNK;  // 208 edge blocks
    int L = 2 * NB * EB;         // 81536 histogram entries
    int sblocks = (L + 511) / 512;     // 160 (<= 512 for scanB)

    char* ws = (char*)d_ws;
    size_t p = 0;
    auto align256 = [&]() { p = (p + 255) & ~(size_t)255; };

    int* H    = (int*)(ws + p); p += (size_t)L * 4;        align256();
    int* tmp  = (int*)(ws + p); p += (size_t)L * 4;        align256();
    int* bsum = (int*)(ws + p); p += 512 * 4;              align256();
    int* boff = (int*)(ws + p); p += 512 * 4;              align256();
    int2* bufD = (int2*)(ws + p); p += (size_t)E * 8;      align256();
    int2* bufS = (int2*)(ws + p); p += (size_t)E * 8;      align256();
    int2* csr  = bufS;  // bufS fully consumed (srcdeg) before csr is written
    int* rowp  = (int*)(ws + p);   p += (size_t)(N + 1) * 4; align256();
    float* rs  = (float*)(ws + p); p += (size_t)N * 4;       align256();
    float* hb1 = (float*)(ws + p); p += (size_t)N * D * 4;   align256();
    float* neigh = (float*)(ws + p); p += (size_t)N * D * 4; align256();
    (void)ws_size; (void)n_in; (void)out_size;

    hist_kernel<<<EB, BS, 0, stream>>>(src, dst, H, E, EB, NB);
    scanA<<<sblocks, 512, 0, stream>>>(H, tmp, bsum, L);
    scanB<<<1, 512, 0, stream>>>(bsum, boff, sblocks);
    scanC<<<sblocks, 512, 0, stream>>>(H, tmp, boff, L);
    partition_kernel<<<EB, BS, 0, stream>>>(src, dst, ew, H, bufD, bufS, E, EB, NB);
    srcdeg_kernel<<<NB, BS, 0, stream>>>(bufS, H, rs, E, EB, NB, N);
    csr_kernel<<<NB, BS, 0, stream>>>(bufD, H, rs, rowp, csr, E, EB, NB, N);

    // h buffers: layer0 -> d_out, layer1 -> hb1, layer2 -> d_out (final)
    const float* hin = feats;
    float* houts[3] = {(float*)d_out, hb1, (float*)d_out};
    for (int Lr = 0; Lr < 3; ++Lr) {
        aggregate<<<(N + 3) / 4, 256, 0, stream>>>(hin, rowp, csr, neigh, N);
        sage_gemm<<<(N + GBM - 1) / GBM, 256, 0, stream>>>(hin, neigh, Wself[Lr], Wneigh[Lr],
                                                           bias[Lr], houts[Lr], N, (Lr < 2) ? 1 : 0);
        hin = houts[Lr];
    }
}